// Round 5
// baseline (289.022 us; speedup 1.0000x reference)
//
#include <hip/hip_runtime.h>
#include <stdint.h>

typedef __bf16 bf16x8 __attribute__((ext_vector_type(8)));
typedef float f32x4 __attribute__((ext_vector_type(4)));

__device__ __forceinline__ unsigned int f2bf(float f) {
  unsigned int u = __float_as_uint(f);
  return (u + 0x7fffu + ((u >> 16) & 1u)) >> 16;  // RNE
}
__device__ __forceinline__ unsigned int pack2(float a, float b) {
  return f2bf(a) | (f2bf(b) << 16);
}

// In-register 16-point FWHT (4 stages, fully unrolled)
__device__ __forceinline__ void fwht16(float v[16]) {
#pragma unroll
  for (int s = 0; s < 4; ++s) {
    const int h = 1 << s;
#pragma unroll
    for (int i = 0; i < 16; ++i) {
      if (!(i & h)) {
        float a = v[i], b = v[i ^ h];
        v[i] = a + b;
        v[i ^ h] = a - b;
      }
    }
  }
}

#define LP(i) ((i) + ((i) >> 5))  // padded LDS index: +1 float per 32

// ---------------------------------------------------------------------------
// K1+K2 merged ("prep"): blocks [0,4096) do per-row FWHT(4096)(x*SU)*(1/64)
// -> bf16 ; blocks [4096,12288) decompress W[m][k] = grid[Qidxs[m][k/8]][k%8].
// ---------------------------------------------------------------------------
__global__ void __launch_bounds__(256) k_prep(const float* __restrict__ X,
                                              const float* __restrict__ SU,
                                              unsigned short* __restrict__ Xh,
                                              const int* __restrict__ Qidxs,
                                              const float* __restrict__ G,
                                              unsigned short* __restrict__ Wh) {
  __shared__ float lds[4224];  // 4096 + 128 pad (unused by decompress blocks)
  const int t = threadIdx.x;
  if (blockIdx.x >= 4096) {
    // ---- decompress ----
    int e = (blockIdx.x - 4096) * 256 + t;
    int idx = Qidxs[e];
    const float4* g = (const float4*)(G + (size_t)idx * 8);
    float4 a = g[0], b = g[1];
    uint4 o;
    o.x = pack2(a.x, a.y);
    o.y = pack2(a.z, a.w);
    o.z = pack2(b.x, b.y);
    o.w = pack2(b.z, b.w);
    ((uint4*)Wh)[e] = o;
    return;
  }
  // ---- FWHT-in ----
  const size_t row = blockIdx.x;
  const float4* xr = (const float4*)(X + row * 4096);
  const float4* su = (const float4*)SU;
  float v[16];
#pragma unroll
  for (int q = 0; q < 4; ++q) {
    float4 a = xr[4 * t + q], s = su[4 * t + q];
    v[4 * q + 0] = a.x * s.x;
    v[4 * q + 1] = a.y * s.y;
    v[4 * q + 2] = a.z * s.z;
    v[4 * q + 3] = a.w * s.w;
  }
  fwht16(v);  // bits 0-3
#pragma unroll
  for (int q = 0; q < 4; ++q) {
    int i0 = 16 * t + 4 * q;
    *(float4*)&lds[LP(i0)] = make_float4(v[4 * q], v[4 * q + 1], v[4 * q + 2], v[4 * q + 3]);
  }
  __syncthreads();
  const int b = ((t >> 4) << 8) | (t & 15);
#pragma unroll
  for (int j = 0; j < 16; ++j) { int i = b + 16 * j; v[j] = lds[LP(i)]; }
  fwht16(v);  // bits 4-7
#pragma unroll
  for (int j = 0; j < 16; ++j) { int i = b + 16 * j; lds[LP(i)] = v[j]; }
  __syncthreads();
#pragma unroll
  for (int j = 0; j < 16; ++j) { int i = t + 256 * j; v[j] = lds[LP(i)]; }
  fwht16(v);  // bits 8-11
  unsigned short* orow = Xh + row * 4096;
#pragma unroll
  for (int j = 0; j < 16; ++j)
    orow[t + 256 * j] = (unsigned short)f2bf(v[j] * 0.015625f);
}

// ---------------------------------------------------------------------------
// K3: GEMM C = A @ B^T (both bf16 [4096][4096], K-major), fp32 out.
// 256x256 tile, BK=64, 8 waves (2Mx4N). ONE-PHASE REGISTER PIPELINE:
// every MFMA cluster consumes fragments ds_read one full phase earlier,
// so the LDS drain hides under the intervening MFMA region. Reads balanced
// 8/4/4/8 per phase (24/K-tile). Accumulation per acc[m][n] stays
// kh0-then-kh1 (numerically identical to previous rounds).
//
// Phase map for group g (tile g in buf p=g&1):
//  ph0: rd {c1A=A[m4-7]k0, bK1=B k1}    ; stage A(g+1)h0->buf p^1 ; MF c0(m0-3,k0)
//  ph1: rd {c2A=A[m0-3]k1}              ; stage A(g+1)h1          ; MF c1(m4-7,k0)
//  ph2: rd {c3A=A[m4-7]k1}              ; stage B(g+2)h0->buf p   ; MF c2(m0-3,k1) ; vmcnt(2)
//  ph3: rd {c0A'=A(g+1)[m0-3]k0, bK0'=B(g+1) k0} from buf p^1
//                                       ; stage B(g+2)h1          ; MF c3(m4-7,k1)
//
// vmcnt ledger (2 loads/stage/wave): entry 4 = B(g+1).
//  ph0 ->6 ; ph1 ->8 ; ph2 ->10, vmcnt(2) retires 8 = B(g+1)+A(g+1) ; ph3 ->4.
//  ph3's next-buffer reads come after vmcnt(2)+ph2 barrier => data visible.
// WAR: A-region of buf p^1 overwritten ph0/1; its last readers were group
//  g-1 ph2/ph3 reads (lgkm-complete before g-1's close). B-region of buf p
//  overwritten ph2/3; last readers ph0's bK1 reads (complete by ph2-region2
//  consumption gate, >=2 barriers before the staged data can land).
// ---------------------------------------------------------------------------
__device__ __forceinline__ void gl2lds16(const unsigned short* g, unsigned short* l) {
  __builtin_amdgcn_global_load_lds(
      (const __attribute__((address_space(1))) void*)g,
      (__attribute__((address_space(3))) void*)l, 16, 0, 0);
}

#define BARX() __builtin_amdgcn_s_barrier()
#define WAITV4() asm volatile("s_waitcnt vmcnt(4)" ::: "memory")
#define WAITV2() asm volatile("s_waitcnt vmcnt(2)" ::: "memory")

// read 4 A-frags (m-steps mb..mb+3, half-K kh) from LDS buffer `buf`
#define RD_A4(dst, buf, mb, kh)                                                \
  _Pragma("unroll") for (int m = 0; m < 4; ++m)                                \
      dst[m] = *(const bf16x8*)&buf[(((wr) << 7) + (((mb) + m) << 4) + frow) * 64 + \
                                    (((((kh) << 2) + jb) ^ sw) << 3)];
// read 4 B-frags (all n, half-K kh)
#define RD_B4(dst, buf, kh)                                                    \
  _Pragma("unroll") for (int n = 0; n < 4; ++n)                                \
      dst[n] = *(const bf16x8*)&buf[(((wc) << 6) + (n << 4) + frow) * 64 +     \
                                    (((((kh) << 2) + jb) ^ sw) << 3)];
// one 16-MFMA cluster: acc[mb..mb+3][0..3] += As[m] * Bs[n]
#define MFC(mb, As, Bs)                                                        \
  __builtin_amdgcn_s_setprio(1);                                               \
  _Pragma("unroll") for (int m = 0; m < 4; ++m)                                \
      _Pragma("unroll") for (int n = 0; n < 4; ++n)                            \
          acc[(mb) + m][n] = __builtin_amdgcn_mfma_f32_16x16x32_bf16(          \
              As[m], Bs[n], acc[(mb) + m][n], 0, 0, 0);                        \
  __builtin_amdgcn_s_setprio(0);

__global__ void __launch_bounds__(512, 2)
k_gemm_bt(const unsigned short* __restrict__ A,
          const unsigned short* __restrict__ B,
          float* __restrict__ C) {
  const int K = 4096, N = 4096;
  __shared__ unsigned short sA[2][256 * 64];
  __shared__ unsigned short sB[2][256 * 64];
  const int tid = threadIdx.x;
  const int lane = tid & 63;
  const int wave = tid >> 6;
  const int wr = wave >> 2;  // 0..1  (M half)
  const int wc = wave & 3;   // 0..3  (N quarter)
  const int frow = lane & 15;
  const int jb = lane >> 4;  // 0..3
  const int sw = frow & 7;   // XOR swizzle key
  const int bn = blockIdx.x, bm = blockIdx.y;
  const size_t rowA0 = (size_t)bm * 256;
  const size_t rowB0 = (size_t)bn * 256;

  f32x4 acc[8][4] = {};
  bf16x8 c0A[4], bK0[4];  // cross-group pipeline registers

  // stage one half-tile (h=0/1 -> rows h*128..h*128+127) of K-tile `ktile`.
  // LDS dest linear (wave-uniform base + lane*16); XOR swizzle applied to the
  // GLOBAL source chunk (m173 pattern).
  auto stage = [&](const unsigned short* __restrict__ G, size_t row0,
                   unsigned short* dst, int h, int ktile) {
    const int kt = (ktile < 64 ? ktile : 0) << 6;  // clamp: tiles >=64 load k=0, never read
#pragma unroll
    for (int l = 0; l < 2; ++l) {
      const int c = (l << 9) + tid;          // 0..1023
      const int r = c >> 3;                  // row within half: 0..127
      const int jg = (c & 7) ^ (r & 7);      // pre-swizzled global chunk
      gl2lds16(G + (row0 + (size_t)((h << 7) + r)) * K + kt + (jg << 3),
               dst + (h << 13) + (c << 3));
    }
  };

  // prologue: tile0 (B,A) -> buf0, B(1) -> buf1; vmcnt(4) retires tile0,
  // leaves B(1)'s 4 loads in flight (entry invariant). Then pre-read
  // cluster0 of tile 0 (c0A, bK0).
  stage(B, rowB0, sB[0], 0, 0);
  stage(B, rowB0, sB[0], 1, 0);
  stage(A, rowA0, sA[0], 0, 0);
  stage(A, rowA0, sA[0], 1, 0);
  stage(B, rowB0, sB[1], 0, 1);
  stage(B, rowB0, sB[1], 1, 1);
  WAITV4();
  BARX();
  RD_A4(c0A, sA[0], 0, 0);
  RD_B4(bK0, sB[0], 0);

#pragma unroll 1
  for (int g = 0; g < 64; ++g) {
    const int p = g & 1;
    const unsigned short* sAp = sA[p];
    const unsigned short* sBp = sB[p];
    const unsigned short* sApN = sA[p ^ 1];  // next tile's A (read at ph3)
    const unsigned short* sBpN = sB[p ^ 1];  // next tile's B (read at ph3)
    unsigned short* sAn = (unsigned short*)sA[p ^ 1];  // stage A(g+1)
    unsigned short* sBn = (unsigned short*)sB[p];      // stage B(g+2)
    bf16x8 c1A[4], c2A[4], c3A[4], bK1[4];
    // ---- ph0
    RD_A4(c1A, sAp, 4, 0);
    RD_B4(bK1, sBp, 1);
    stage(A, rowA0, sAn, 0, g + 1);
    BARX();
    MFC(0, c0A, bK0);          // (m0-3, kh0) — frags from previous ph3
    BARX();
    // ---- ph1
    RD_A4(c2A, sAp, 0, 1);
    stage(A, rowA0, sAn, 1, g + 1);
    BARX();
    MFC(4, c1A, bK0);          // (m4-7, kh0)
    BARX();
    // ---- ph2
    RD_A4(c3A, sAp, 4, 1);
    stage(B, rowB0, sBn, 0, g + 2);
    BARX();
    MFC(0, c2A, bK1);          // (m0-3, kh1)
    WAITV2();                  // retire B(g+1)+A(g+1) before ph3's reads
    BARX();
    // ---- ph3
    RD_A4(c0A, sApN, 0, 0);    // next tile cluster0
    RD_B4(bK0, sBpN, 0);
    stage(B, rowB0, sBn, 1, g + 2);
    BARX();
    MFC(4, c3A, bK1);          // (m4-7, kh1)
    BARX();
  }

  // epilogue: C/D layout col = lane&15, row = (lane>>4)*4 + reg
  const int rbase = bm * 256 + (wr << 7) + (jb << 2);
  const int cbase = bn * 256 + (wc << 6) + frow;
#pragma unroll
  for (int m = 0; m < 8; ++m)
#pragma unroll
    for (int n = 0; n < 4; ++n) {
      float* cp = C + (size_t)(rbase + (m << 4)) * N + cbase + (n << 4);
#pragma unroll
      for (int r = 0; r < 4; ++r) cp[(size_t)r * N] = acc[m][n][r];
    }
}

// ---------------------------------------------------------------------------
// K4: per-row FWHT(4096) on fp32 output ; * SV * (1/64)
// ---------------------------------------------------------------------------
__global__ void __launch_bounds__(256) k_fwht_out(float* __restrict__ Y,
                                                  const float* __restrict__ SV) {
  __shared__ float lds[4224];
  const int t = threadIdx.x;
  const size_t row = blockIdx.x;
  float* yrow = Y + row * 4096;
  const float4* yr = (const float4*)yrow;
  float v[16];
#pragma unroll
  for (int q = 0; q < 4; ++q) {
    float4 a = yr[4 * t + q];
    v[4 * q + 0] = a.x;
    v[4 * q + 1] = a.y;
    v[4 * q + 2] = a.z;
    v[4 * q + 3] = a.w;
  }
  fwht16(v);  // bits 0-3
#pragma unroll
  for (int q = 0; q < 4; ++q) {
    int i0 = 16 * t + 4 * q;
    *(float4*)&lds[LP(i0)] = make_float4(v[4 * q], v[4 * q + 1], v[4 * q + 2], v[4 * q + 3]);
  }
  __syncthreads();
  const int b = ((t >> 4) << 8) | (t & 15);
#pragma unroll
  for (int j = 0; j < 16; ++j) { int i = b + 16 * j; v[j] = lds[LP(i)]; }
  fwht16(v);  // bits 4-7
#pragma unroll
  for (int j = 0; j < 16; ++j) { int i = b + 16 * j; lds[LP(i)] = v[j]; }
  __syncthreads();
#pragma unroll
  for (int j = 0; j < 16; ++j) { int i = t + 256 * j; v[j] = lds[LP(i)]; }
  fwht16(v);  // bits 8-11
#pragma unroll
  for (int j = 0; j < 16; ++j) {
    int i = t + 256 * j;
    yrow[i] = v[j] * SV[i] * 0.015625f;
  }
}

// ---------------------------------------------------------------------------
extern "C" void kernel_launch(void* const* d_in, const int* in_sizes, int n_in,
                              void* d_out, int out_size, void* d_ws, size_t ws_size,
                              hipStream_t stream) {
  const float* X     = (const float*)d_in[0];
  const float* SU    = (const float*)d_in[1];
  const float* SV    = (const float*)d_in[2];
  const float* G     = (const float*)d_in[3];
  const int*   Qidxs = (const int*)d_in[4];
  float* out = (float*)d_out;

  unsigned short* Xh = (unsigned short*)d_ws;
  unsigned short* Wh = Xh + (size_t)4096 * 4096;

  k_prep<<<4096 + 8192, 256, 0, stream>>>(X, SU, Xh, Qidxs, G, Wh);
  k_gemm_bt<<<dim3(16, 16), 512, 0, stream>>>(Xh, Wh, out);
  k_fwht_out<<<4096, 256, 0, stream>>>(out, SV);
}

// Round 6
// 288.622 us; speedup vs baseline: 1.0014x; 1.0014x over previous
//
#include <hip/hip_runtime.h>
#include <stdint.h>

typedef __bf16 bf16x8 __attribute__((ext_vector_type(8)));
typedef float f32x4 __attribute__((ext_vector_type(4)));

__device__ __forceinline__ unsigned int f2bf(float f) {
  unsigned int u = __float_as_uint(f);
  return (u + 0x7fffu + ((u >> 16) & 1u)) >> 16;  // RNE
}
__device__ __forceinline__ unsigned int pack2(float a, float b) {
  return f2bf(a) | (f2bf(b) << 16);
}

// In-register 16-point FWHT (4 stages, fully unrolled)
__device__ __forceinline__ void fwht16(float v[16]) {
#pragma unroll
  for (int s = 0; s < 4; ++s) {
    const int h = 1 << s;
#pragma unroll
    for (int i = 0; i < 16; ++i) {
      if (!(i & h)) {
        float a = v[i], b = v[i ^ h];
        v[i] = a + b;
        v[i ^ h] = a - b;
      }
    }
  }
}

#define LP(i) ((i) + ((i) >> 5))  // padded LDS index: +1 float per 32

// ---------------------------------------------------------------------------
// K1+K2 merged ("prep"): blocks [0,4096) do per-row FWHT(4096)(x*SU)*(1/64)
// -> bf16 ; blocks [4096,12288) decompress W[m][k] = grid[Qidxs[m][k/8]][k%8].
// ---------------------------------------------------------------------------
__global__ void __launch_bounds__(256) k_prep(const float* __restrict__ X,
                                              const float* __restrict__ SU,
                                              unsigned short* __restrict__ Xh,
                                              const int* __restrict__ Qidxs,
                                              const float* __restrict__ G,
                                              unsigned short* __restrict__ Wh) {
  __shared__ float lds[4224];  // 4096 + 128 pad (unused by decompress blocks)
  const int t = threadIdx.x;
  if (blockIdx.x >= 4096) {
    // ---- decompress ----
    int e = (blockIdx.x - 4096) * 256 + t;
    int idx = Qidxs[e];
    const float4* g = (const float4*)(G + (size_t)idx * 8);
    float4 a = g[0], b = g[1];
    uint4 o;
    o.x = pack2(a.x, a.y);
    o.y = pack2(a.z, a.w);
    o.z = pack2(b.x, b.y);
    o.w = pack2(b.z, b.w);
    ((uint4*)Wh)[e] = o;
    return;
  }
  // ---- FWHT-in ----
  const size_t row = blockIdx.x;
  const float4* xr = (const float4*)(X + row * 4096);
  const float4* su = (const float4*)SU;
  float v[16];
#pragma unroll
  for (int q = 0; q < 4; ++q) {
    float4 a = xr[4 * t + q], s = su[4 * t + q];
    v[4 * q + 0] = a.x * s.x;
    v[4 * q + 1] = a.y * s.y;
    v[4 * q + 2] = a.z * s.z;
    v[4 * q + 3] = a.w * s.w;
  }
  fwht16(v);  // bits 0-3
#pragma unroll
  for (int q = 0; q < 4; ++q) {
    int i0 = 16 * t + 4 * q;
    *(float4*)&lds[LP(i0)] = make_float4(v[4 * q], v[4 * q + 1], v[4 * q + 2], v[4 * q + 3]);
  }
  __syncthreads();
  const int b = ((t >> 4) << 8) | (t & 15);
#pragma unroll
  for (int j = 0; j < 16; ++j) { int i = b + 16 * j; v[j] = lds[LP(i)]; }
  fwht16(v);  // bits 4-7
#pragma unroll
  for (int j = 0; j < 16; ++j) { int i = b + 16 * j; lds[LP(i)] = v[j]; }
  __syncthreads();
#pragma unroll
  for (int j = 0; j < 16; ++j) { int i = t + 256 * j; v[j] = lds[LP(i)]; }
  fwht16(v);  // bits 8-11
  unsigned short* orow = Xh + row * 4096;
#pragma unroll
  for (int j = 0; j < 16; ++j)
    orow[t + 256 * j] = (unsigned short)f2bf(v[j] * 0.015625f);
}

// ---------------------------------------------------------------------------
// K3: GEMM C = A @ B^T (both bf16 [4096][4096], K-major), fp32 out.
// 256x256 tile, BK=64, 8 waves (2Mx4N).
// R6 structure: FOUR single-barrier regions per K-tile. Each region:
//   { 16 independent MFMAs (operands ds_read one region earlier)
//     || 4-8 ds_reads for the NEXT region's MFMAs
//     || 1 staging half-tile (global_load_lds) }
//   then lgkmcnt(0) (free: reads had the whole MFMA region to drain;
//   also guarantees all waves' reads of a region complete before any
//   wave's post-barrier staging can overwrite it) ; s_barrier.
// Barriers halved vs R1-R5 (4/K-tile); reads co-scheduled with MFMA in one
// region so the compiler interleaves issue and the drain hides under MFMA.
//
// Cluster map, group g (tile g in buf p=g&1); next group's MFC0 operands
// read in R3 from buf p^1:
//  R0: MFC0(m0-3,k0)  rd c1A=A[m4-7]k0        stage A(g+1)h0 -> p^1
//  R1: MFC1(m4-7,k0)  rd c2A=A[m0-3]k1, bK1   stage A(g+1)h1
//  R2: MFC2(m0-3,k1)  rd c3A=A[m4-7]k1        stage B(g+2)h0 -> p ; vmcnt(2)
//  R3: MFC3(m4-7,k1)  rd c0A'=A(g+1)k0, bK0'  stage B(g+2)h1
//
// vmcnt ledger (2 loads/stage/wave): entry 4 = B(g+1).
//  R0 ->6 ; R1 ->8 ; R2 ->10, vmcnt(2) retires 8 = B(g+1)+A(g+1), leaves
//  B(g+2)h0(2) ; R3 ->4. R3's p^1 reads come after vmcnt(2)+R2 barrier ✓.
// WAR: A-region p^1 staged R0/R1: old contents (A(g-1)) last read in g-1's
//  R2 (drained by its lgkmcnt(0)+barrier). B-region p staged R2/R3: old
//  contents (B(g)) last read R1 (bK1), drained by R1's lgkmcnt(0)+barrier.
// Accumulation per acc[m][n]: k0 then k1 — numerically identical to R1-R5.
// ---------------------------------------------------------------------------
__device__ __forceinline__ void gl2lds16(const unsigned short* g, unsigned short* l) {
  __builtin_amdgcn_global_load_lds(
      (const __attribute__((address_space(1))) void*)g,
      (__attribute__((address_space(3))) void*)l, 16, 0, 0);
}

#define BARX() __builtin_amdgcn_s_barrier()
#define WAITV4() asm volatile("s_waitcnt vmcnt(4)" ::: "memory")
#define WAITV2() asm volatile("s_waitcnt vmcnt(2)" ::: "memory")
#define WAITL0() asm volatile("s_waitcnt lgkmcnt(0)" ::: "memory")

// read 4 A-frags (m-steps mb..mb+3, half-K kh) from LDS buffer `buf`
#define RD_A4(dst, buf, mb, kh)                                                \
  _Pragma("unroll") for (int m = 0; m < 4; ++m)                                \
      dst[m] = *(const bf16x8*)&buf[(((wr) << 7) + (((mb) + m) << 4) + frow) * 64 + \
                                    (((((kh) << 2) + jb) ^ sw) << 3)];
// read 4 B-frags (all n, half-K kh)
#define RD_B4(dst, buf, kh)                                                    \
  _Pragma("unroll") for (int n = 0; n < 4; ++n)                                \
      dst[n] = *(const bf16x8*)&buf[(((wc) << 6) + (n << 4) + frow) * 64 +     \
                                    (((((kh) << 2) + jb) ^ sw) << 3)];
// one 16-MFMA cluster: acc[mb..mb+3][0..3] += As[m] * Bs[n] (all independent)
#define MFC(mb, As, Bs)                                                        \
  __builtin_amdgcn_s_setprio(1);                                               \
  _Pragma("unroll") for (int m = 0; m < 4; ++m)                                \
      _Pragma("unroll") for (int n = 0; n < 4; ++n)                            \
          acc[(mb) + m][n] = __builtin_amdgcn_mfma_f32_16x16x32_bf16(          \
              As[m], Bs[n], acc[(mb) + m][n], 0, 0, 0);                        \
  __builtin_amdgcn_s_setprio(0);

__global__ void __launch_bounds__(512, 2)
k_gemm_bt(const unsigned short* __restrict__ A,
          const unsigned short* __restrict__ B,
          float* __restrict__ C) {
  const int K = 4096, N = 4096;
  __shared__ unsigned short sA[2][256 * 64];
  __shared__ unsigned short sB[2][256 * 64];
  const int tid = threadIdx.x;
  const int lane = tid & 63;
  const int wave = tid >> 6;
  const int wr = wave >> 2;  // 0..1  (M half)
  const int wc = wave & 3;   // 0..3  (N quarter)
  const int frow = lane & 15;
  const int jb = lane >> 4;  // 0..3
  const int sw = frow & 7;   // XOR swizzle key
  const int bn = blockIdx.x, bm = blockIdx.y;
  const size_t rowA0 = (size_t)bm * 256;
  const size_t rowB0 = (size_t)bn * 256;

  f32x4 acc[8][4] = {};
  bf16x8 c0A[4], bK0[4];  // cross-group pipeline registers

  // stage one half-tile (h=0/1 -> rows h*128..h*128+127) of K-tile `ktile`.
  // LDS dest linear (wave-uniform base + lane*16); XOR swizzle applied to the
  // GLOBAL source chunk (m173 pattern).
  auto stage = [&](const unsigned short* __restrict__ G, size_t row0,
                   unsigned short* dst, int h, int ktile) {
    const int kt = (ktile < 64 ? ktile : 0) << 6;  // clamp: tiles >=64 load k=0, never read
#pragma unroll
    for (int l = 0; l < 2; ++l) {
      const int c = (l << 9) + tid;          // 0..1023
      const int r = c >> 3;                  // row within half: 0..127
      const int jg = (c & 7) ^ (r & 7);      // pre-swizzled global chunk
      gl2lds16(G + (row0 + (size_t)((h << 7) + r)) * K + kt + (jg << 3),
               dst + (h << 13) + (c << 3));
    }
  };

  // prologue: tile0 (B,A) -> buf0, B(1) -> buf1; vmcnt(4) retires tile0,
  // leaves B(1)'s 4 loads in flight (entry invariant). Then pre-read
  // cluster0 of tile 0 (c0A, bK0) after the visibility barrier.
  stage(B, rowB0, sB[0], 0, 0);
  stage(B, rowB0, sB[0], 1, 0);
  stage(A, rowA0, sA[0], 0, 0);
  stage(A, rowA0, sA[0], 1, 0);
  stage(B, rowB0, sB[1], 0, 1);
  stage(B, rowB0, sB[1], 1, 1);
  WAITV4();
  BARX();
  RD_A4(c0A, sA[0], 0, 0);
  RD_B4(bK0, sB[0], 0);

#pragma unroll 1
  for (int g = 0; g < 64; ++g) {
    const int p = g & 1;
    const unsigned short* sAp = sA[p];
    const unsigned short* sBp = sB[p];
    const unsigned short* sApN = sA[p ^ 1];  // A(g+1), read in R3
    const unsigned short* sBpN = sB[p ^ 1];  // B(g+1), read in R3
    unsigned short* sAn = (unsigned short*)sA[p ^ 1];  // stage A(g+1)
    unsigned short* sBn = (unsigned short*)sB[p];      // stage B(g+2)
    bf16x8 c1A[4], c2A[4], c3A[4], bK1[4];
    // ---- R0
    MFC(0, c0A, bK0);
    RD_A4(c1A, sAp, 4, 0);
    stage(A, rowA0, sAn, 0, g + 1);
    WAITL0();
    BARX();
    // ---- R1
    MFC(4, c1A, bK0);
    RD_A4(c2A, sAp, 0, 1);
    RD_B4(bK1, sBp, 1);
    stage(A, rowA0, sAn, 1, g + 1);
    WAITL0();
    BARX();
    // ---- R2
    MFC(0, c2A, bK1);
    RD_A4(c3A, sAp, 4, 1);
    stage(B, rowB0, sBn, 0, g + 2);
    WAITV2();
    WAITL0();
    BARX();
    // ---- R3
    MFC(4, c3A, bK1);
    RD_A4(c0A, sApN, 0, 0);
    RD_B4(bK0, sBpN, 0);
    stage(B, rowB0, sBn, 1, g + 2);
    WAITL0();
    BARX();
  }

  // epilogue: C/D layout col = lane&15, row = (lane>>4)*4 + reg
  const int rbase = bm * 256 + (wr << 7) + (jb << 2);
  const int cbase = bn * 256 + (wc << 6) + frow;
#pragma unroll
  for (int m = 0; m < 8; ++m)
#pragma unroll
    for (int n = 0; n < 4; ++n) {
      float* cp = C + (size_t)(rbase + (m << 4)) * N + cbase + (n << 4);
#pragma unroll
      for (int r = 0; r < 4; ++r) cp[(size_t)r * N] = acc[m][n][r];
    }
}

// ---------------------------------------------------------------------------
// K4: per-row FWHT(4096) on fp32 output ; * SV * (1/64)
// ---------------------------------------------------------------------------
__global__ void __launch_bounds__(256) k_fwht_out(float* __restrict__ Y,
                                                  const float* __restrict__ SV) {
  __shared__ float lds[4224];
  const int t = threadIdx.x;
  const size_t row = blockIdx.x;
  float* yrow = Y + row * 4096;
  const float4* yr = (const float4*)yrow;
  float v[16];
#pragma unroll
  for (int q = 0; q < 4; ++q) {
    float4 a = yr[4 * t + q];
    v[4 * q + 0] = a.x;
    v[4 * q + 1] = a.y;
    v[4 * q + 2] = a.z;
    v[4 * q + 3] = a.w;
  }
  fwht16(v);  // bits 0-3
#pragma unroll
  for (int q = 0; q < 4; ++q) {
    int i0 = 16 * t + 4 * q;
    *(float4*)&lds[LP(i0)] = make_float4(v[4 * q], v[4 * q + 1], v[4 * q + 2], v[4 * q + 3]);
  }
  __syncthreads();
  const int b = ((t >> 4) << 8) | (t & 15);
#pragma unroll
  for (int j = 0; j < 16; ++j) { int i = b + 16 * j; v[j] = lds[LP(i)]; }
  fwht16(v);  // bits 4-7
#pragma unroll
  for (int j = 0; j < 16; ++j) { int i = b + 16 * j; lds[LP(i)] = v[j]; }
  __syncthreads();
#pragma unroll
  for (int j = 0; j < 16; ++j) { int i = t + 256 * j; v[j] = lds[LP(i)]; }
  fwht16(v);  // bits 8-11
#pragma unroll
  for (int j = 0; j < 16; ++j) {
    int i = t + 256 * j;
    yrow[i] = v[j] * SV[i] * 0.015625f;
  }
}

// ---------------------------------------------------------------------------
extern "C" void kernel_launch(void* const* d_in, const int* in_sizes, int n_in,
                              void* d_out, int out_size, void* d_ws, size_t ws_size,
                              hipStream_t stream) {
  const float* X     = (const float*)d_in[0];
  const float* SU    = (const float*)d_in[1];
  const float* SV    = (const float*)d_in[2];
  const float* G     = (const float*)d_in[3];
  const int*   Qidxs = (const int*)d_in[4];
  float* out = (float*)d_out;

  unsigned short* Xh = (unsigned short*)d_ws;
  unsigned short* Wh = Xh + (size_t)4096 * 4096;

  k_prep<<<4096 + 8192, 256, 0, stream>>>(X, SU, Xh, Qidxs, G, Wh);
  k_gemm_bt<<<dim3(16, 16), 512, 0, stream>>>(Xh, Wh, out);
  k_fwht_out<<<4096, 256, 0, stream>>>(out, SV);
}